// Round 6
// baseline (773.389 us; speedup 1.0000x reference)
//
#include <hip/hip_runtime.h>
#include <hip/hip_bf16.h>
#include <stdint.h>

typedef uint16_t u16;
typedef __attribute__((ext_vector_type(8))) __bf16 bf16x8;
typedef __attribute__((ext_vector_type(4))) float f32x4;
typedef __attribute__((ext_vector_type(4))) u16 u16x4;

// Problem constants
#define BSZ   256
#define NN    512
#define TT    12
#define FF    12
#define HID   1536
#define INSZ  6144    // N*F = LSTM input size
#define GATES 6144    // 4*HID
#define MROWS 3072    // FF*BSZ rows of the hoisted input GEMM

static __device__ __forceinline__ u16 f2bf(float x) {
  uint32_t u = __builtin_bit_cast(uint32_t, x);
  u += 0x7fffu + ((u >> 16) & 1u);   // RNE
  return (u16)(u >> 16);
}

static __device__ __forceinline__ float sigm(float x) {
  return 1.0f / (1.0f + expf(-x));
}

// ---------------- fp32 -> bf16 convert (4 elems/thread, grid-stride) ----------------
__global__ void cvt_bf16(const float* __restrict__ in, u16* __restrict__ out, long n4) {
  long stride = (long)gridDim.x * blockDim.x;
  for (long i = (long)blockIdx.x * blockDim.x + threadIdx.x; i < n4; i += stride) {
    float4 v = ((const float4*)in)[i];
    u16x4 r = { f2bf(v.x), f2bf(v.y), f2bf(v.z), f2bf(v.w) };
    ((u16x4*)out)[i] = r;
  }
}

// ---------------- pack X (B,N,T,F) -> A (MROWS=f*256+b, 6144=k) bf16 ----------------
__global__ void pack_x(const float* __restrict__ X, u16* __restrict__ Ax) {
  int idx = blockIdx.x * blockDim.x + threadIdx.x;   // one (b,k) per thread
  int b = idx / INSZ;
  int k = idx - b * INSZ;
  const float* xp = X + (size_t)b * (INSZ * FF) + (size_t)k * FF;
  float v[FF];
#pragma unroll
  for (int f = 0; f < FF; ++f) v[f] = xp[f];
#pragma unroll
  for (int f = 0; f < FF; ++f)
    Ax[(size_t)(f * BSZ + b) * INSZ + k] = f2bf(v[f]);
}

// =====================================================================
// Deep-pipelined bf16 GEMM: C(MxN) = A(MxK) * Bt(NxK)^T + bias
// Tile 192x384, BK=64, 512 threads (8 waves, 2x4), per-wave 96x96.
// R6: barriers cut 7 -> 2 per K-tile. Only the two cross-wave hazards keep
// barriers: (a) post-vmcnt tile-visibility at iter entry, (b) end-of-iter
// (all buffer-p reads drained by their MFMA uses) before next iter's GLL
// writes to p. All 24 frag reads issue early; compiler's precise per-use
// lgkmcnt waits start each MFMA quadrant as soon as its operands land.
// Waves drift within a K-tile -> read/MFMA overlap across waves per SIMD.
// =====================================================================
#define BM8 192
#define BN8 384
#define LDSA_SZ 24576   // 192*64*2
#define LDSB_SZ 49152   // 384*64*2
#define LDS_TOTAL (2 * (LDSA_SZ + LDSB_SZ))   // 147456

#define GLL(src, dst)                                                          \
  __builtin_amdgcn_global_load_lds(                                            \
      (const __attribute__((address_space(1))) void*)(src),                    \
      (__attribute__((address_space(3))) void*)(dst), 16, 0, 0)

#define SBAR() asm volatile("s_barrier" ::: "memory")

__global__ __launch_bounds__(512, 2) void gemm8p(
    const u16* __restrict__ A, const u16* __restrict__ Bt,
    const float* __restrict__ bi, const float* __restrict__ bh,
    float* __restrict__ C, int M, int N, int K) {
  extern __shared__ __align__(16) char lds[];
  const int tid  = threadIdx.x;
  const int lane = tid & 63;
  const int wid  = tid >> 6;
  const int wr   = wid >> 2;   // 0..1
  const int wc   = wid & 3;    // 0..3

  // bijective XCD swizzle (gridDim.x % 8 == 0)
  const int nbx  = N / BN8;
  const int cpx  = gridDim.x >> 3;
  const int orig = blockIdx.x;
  const int wgid = (orig & 7) * cpx + (orig >> 3);
  const int m0   = (wgid / nbx) * BM8;
  const int n0   = (wgid % nbx) * BN8;

  // fragment-read per-lane constants (logical colbyte ^ ((row&7)<<4))
  const int fr    = lane & 15;
  const int kb    = (lane >> 4) << 4;
  const int swz   = (fr & 7) << 4;
  const int colp0 = kb ^ swz;          // kstep 0
  const int colp1 = (64 | kb) ^ swz;   // kstep 1

  // staging per-lane constants: linear LDS dest, inverse-swizzled source
  const int srow = tid >> 3;                                  // 0..63
  const int scb  = ((tid & 7) << 4) ^ ((srow & 7) << 4);      // byte col
  const u16* gA = A  + (size_t)(m0 + srow) * K + (scb >> 1);
  const u16* gB = Bt + (size_t)(n0 + srow) * K + (scb >> 1);
  const int wdst = wid << 10;   // wid*1024 bytes (lane*16 added by HW)

  char* ldsA = lds;
  char* ldsB = lds + 2 * LDSA_SZ;
  char* aRowB = ldsA + (wr * 96 + fr) * 128;   // + p*LDSA_SZ at use
  char* bRowB = ldsB + (wc * 96 + fr) * 128;   // + p*LDSB_SZ at use

  f32x4 acc[6][6] = {};
  const int NT = K >> 6;

  // prologue: stage tile 0 into buffer 0 (3 A chunks + 6 B chunks)
#pragma unroll
  for (int c = 0; c < 3; ++c) GLL(gA + (size_t)c * 64 * K, ldsA + c * 8192 + wdst);
#pragma unroll
  for (int c = 0; c < 6; ++c) GLL(gB + (size_t)c * 64 * K, ldsB + c * 8192 + wdst);

  for (int t = 0; t < NT; ++t) {
    const int p = t & 1;
    char* aRow = aRowB + p * LDSA_SZ;
    char* bRow = bRowB + p * LDSB_SZ;
    char* An = ldsA + (p ^ 1) * LDSA_SZ;
    char* Bn = ldsB + (p ^ 1) * LDSB_SZ;
    const u16* gAn = gA + (size_t)(t + 1) * 64;
    const u16* gBn = gB + (size_t)(t + 1) * 64;
    const bool pf = (t + 1 < NT);

    bf16x8 a0[2][3], a1[2][3], b0[2][3], b1[2][3];

    // ---- iter entry: stage A(t+1); wait tile t staged; visibility barrier
    if (pf) {
#pragma unroll
      for (int c = 0; c < 3; ++c) GLL(gAn + (size_t)c * 64 * K, An + c * 8192 + wdst);
      asm volatile("s_waitcnt vmcnt(3)" ::: "memory");
    } else {
      asm volatile("s_waitcnt vmcnt(0)" ::: "memory");
    }
    SBAR();

    // ---- issue all fragment reads early (compiler waits per-use)
#pragma unroll
    for (int i = 0; i < 3; ++i) {
      a0[0][i] = *(const bf16x8*)(aRow + i * 2048 + colp0);
      a0[1][i] = *(const bf16x8*)(aRow + i * 2048 + colp1);
      b0[0][i] = *(const bf16x8*)(bRow + i * 2048 + colp0);
      b0[1][i] = *(const bf16x8*)(bRow + i * 2048 + colp1);
      b1[0][i] = *(const bf16x8*)(bRow + (3 + i) * 2048 + colp0);
      b1[1][i] = *(const bf16x8*)(bRow + (3 + i) * 2048 + colp1);
      a1[0][i] = *(const bf16x8*)(aRow + (3 + i) * 2048 + colp0);
      a1[1][i] = *(const bf16x8*)(aRow + (3 + i) * 2048 + colp1);
    }

    // ---- q00: a0 x b0
    __builtin_amdgcn_s_setprio(1);
#pragma unroll
    for (int i = 0; i < 3; ++i)
#pragma unroll
      for (int j = 0; j < 3; ++j) {
        acc[i][j] = __builtin_amdgcn_mfma_f32_16x16x32_bf16(a0[0][i], b0[0][j], acc[i][j], 0, 0, 0);
        acc[i][j] = __builtin_amdgcn_mfma_f32_16x16x32_bf16(a0[1][i], b0[1][j], acc[i][j], 0, 0, 0);
      }
    __builtin_amdgcn_s_setprio(0);
    if (pf) {
      GLL(gBn + (size_t)0 * 64 * K, Bn + 0 * 8192 + wdst);
      GLL(gBn + (size_t)1 * 64 * K, Bn + 1 * 8192 + wdst);
    }

    // ---- q01: a0 x b1
    __builtin_amdgcn_s_setprio(1);
#pragma unroll
    for (int i = 0; i < 3; ++i)
#pragma unroll
      for (int j = 0; j < 3; ++j) {
        acc[i][3 + j] = __builtin_amdgcn_mfma_f32_16x16x32_bf16(a0[0][i], b1[0][j], acc[i][3 + j], 0, 0, 0);
        acc[i][3 + j] = __builtin_amdgcn_mfma_f32_16x16x32_bf16(a0[1][i], b1[1][j], acc[i][3 + j], 0, 0, 0);
      }
    __builtin_amdgcn_s_setprio(0);
    if (pf) {
      GLL(gBn + (size_t)2 * 64 * K, Bn + 2 * 8192 + wdst);
      GLL(gBn + (size_t)3 * 64 * K, Bn + 3 * 8192 + wdst);
    }

    // ---- q11: a1 x b1
    __builtin_amdgcn_s_setprio(1);
#pragma unroll
    for (int i = 0; i < 3; ++i)
#pragma unroll
      for (int j = 0; j < 3; ++j) {
        acc[3 + i][3 + j] = __builtin_amdgcn_mfma_f32_16x16x32_bf16(a1[0][i], b1[0][j], acc[3 + i][3 + j], 0, 0, 0);
        acc[3 + i][3 + j] = __builtin_amdgcn_mfma_f32_16x16x32_bf16(a1[1][i], b1[1][j], acc[3 + i][3 + j], 0, 0, 0);
      }
    __builtin_amdgcn_s_setprio(0);
    if (pf) {
      GLL(gBn + (size_t)4 * 64 * K, Bn + 4 * 8192 + wdst);
      GLL(gBn + (size_t)5 * 64 * K, Bn + 5 * 8192 + wdst);
    }

    // ---- q10: a1 x b0
    __builtin_amdgcn_s_setprio(1);
#pragma unroll
    for (int i = 0; i < 3; ++i)
#pragma unroll
      for (int j = 0; j < 3; ++j) {
        acc[3 + i][j] = __builtin_amdgcn_mfma_f32_16x16x32_bf16(a1[0][i], b0[0][j], acc[3 + i][j], 0, 0, 0);
        acc[3 + i][j] = __builtin_amdgcn_mfma_f32_16x16x32_bf16(a1[1][i], b0[1][j], acc[3 + i][j], 0, 0, 0);
      }
    __builtin_amdgcn_s_setprio(0);

    // ---- end-of-iter: all buffer-p reads are drained (used by MFMAs above);
    // barrier before any wave's next-iter GLL writes into buffer p.
    SBAR();
  }

  // epilogue: C = acc + (b_ih + b_hh)[col]
  const int r0 = (lane >> 4) << 2;
  const int cc = lane & 15;
#pragma unroll
  for (int j = 0; j < 6; ++j) {
    const int col = n0 + wc * 96 + j * 16 + cc;
    const float bv = bi[col] + bh[col];
#pragma unroll
    for (int i = 0; i < 6; ++i) {
      const size_t rbase = (size_t)(m0 + wr * 96 + i * 16 + r0) * N + col;
#pragma unroll
      for (int r = 0; r < 4; ++r)
        C[rbase + (size_t)r * N] = acc[i][j][r] + bv;
    }
  }
}

// =====================================================================
// SplitK=2 pipelined step GEMM: HW_s(256x6144) = h(256x768-half) @ Whh^T
// 64x64 tile, BK=64, 4 waves (each a 32x32 quadrant), dbuf LDS 32KB,
// counted vmcnt(4), grid (96,4,2) = 768 blocks = 3.0/CU.
// =====================================================================
#define WAIT_LGKM0()                                                           \
  do {                                                                         \
    asm volatile("s_waitcnt lgkmcnt(0)" ::: "memory");                         \
    __builtin_amdgcn_sched_barrier(0);                                         \
  } while (0)

__global__ __launch_bounds__(256, 4) void gemm_step(
    const u16* __restrict__ A,   // hbf (256 x 1536)
    const u16* __restrict__ Bt,  // Whhb (6144 x 1536)
    float* __restrict__ HW) {    // partials: split s at HW + s*BSZ*GATES
  __shared__ __align__(16) char lds[32768];
  const int tid  = threadIdx.x;
  const int lane = tid & 63;
  const int wid  = tid >> 6;
  const int wr   = wid >> 1;   // 0..1
  const int wc   = wid & 1;    // 0..1
  const int n0   = blockIdx.x * 64;
  const int m0   = blockIdx.y * 64;
  const int s    = blockIdx.z;
  const int K    = HID;
  const int koff = s * 768;

  // fragment-read constants (same scheme as gemm8p)
  const int fr    = lane & 15;
  const int kb    = (lane >> 4) << 4;
  const int swz   = (fr & 7) << 4;
  const int colp0 = kb ^ swz;
  const int colp1 = (64 | kb) ^ swz;

  // staging: thread t -> row = t>>3 (0..31), cb = (t&7)*16; pass 1 adds 32 rows
  const int srow = tid >> 3;
  const int scb  = ((tid & 7) << 4) ^ ((srow & 7) << 4);
  const u16* gA = A  + (size_t)(m0 + srow) * K + koff + (scb >> 1);
  const u16* gB = Bt + (size_t)(n0 + srow) * K + koff + (scb >> 1);
  const int wdst = wid << 10;

  char* ldsA = lds;            // [2][8192]
  char* ldsB = lds + 16384;    // [2][8192]
  char* aRowB = ldsA + (wr * 32 + fr) * 128;
  char* bRowB = ldsB + (wc * 32 + fr) * 128;

  f32x4 acc[2][2] = {};
  const int NT = 768 >> 6;   // 12

  // prologue: stage tile 0 into buffer 0
  GLL(gA,                    ldsA + wdst);
  GLL(gA + (size_t)32 * K,   ldsA + 4096 + wdst);
  GLL(gB,                    ldsB + wdst);
  GLL(gB + (size_t)32 * K,   ldsB + 4096 + wdst);

  for (int t = 0; t < NT; ++t) {
    const int p = t & 1;
    char* aRow = aRowB + p * 8192;
    char* bRow = bRowB + p * 8192;
    char* An = ldsA + (p ^ 1) * 8192;
    char* Bn = ldsB + (p ^ 1) * 8192;
    const u16* gAn = gA + (size_t)(t + 1) * 64;
    const u16* gBn = gB + (size_t)(t + 1) * 64;

    if (t + 1 < NT) {
      GLL(gAn,                  An + wdst);
      GLL(gAn + (size_t)32 * K, An + 4096 + wdst);
      GLL(gBn,                  Bn + wdst);
      GLL(gBn + (size_t)32 * K, Bn + 4096 + wdst);
      asm volatile("s_waitcnt vmcnt(4)" ::: "memory");
    } else {
      asm volatile("s_waitcnt vmcnt(0)" ::: "memory");
    }
    SBAR();

    bf16x8 a[2][2], b[2][2];
#pragma unroll
    for (int i = 0; i < 2; ++i) {
      a[0][i] = *(const bf16x8*)(aRow + i * 2048 + colp0);
      a[1][i] = *(const bf16x8*)(aRow + i * 2048 + colp1);
      b[0][i] = *(const bf16x8*)(bRow + i * 2048 + colp0);
      b[1][i] = *(const bf16x8*)(bRow + i * 2048 + colp1);
    }
    WAIT_LGKM0();
    __builtin_amdgcn_s_setprio(1);
#pragma unroll
    for (int i = 0; i < 2; ++i)
#pragma unroll
      for (int j = 0; j < 2; ++j) {
        acc[i][j] = __builtin_amdgcn_mfma_f32_16x16x32_bf16(a[0][i], b[0][j], acc[i][j], 0, 0, 0);
        acc[i][j] = __builtin_amdgcn_mfma_f32_16x16x32_bf16(a[1][i], b[1][j], acc[i][j], 0, 0, 0);
      }
    __builtin_amdgcn_s_setprio(0);
    SBAR();
  }

  float* Cp = HW + (size_t)s * BSZ * GATES;
  const int r0 = (lane >> 4) << 2;
  const int cc = lane & 15;
#pragma unroll
  for (int i = 0; i < 2; ++i)
#pragma unroll
    for (int j = 0; j < 2; ++j) {
      const size_t rbase = (size_t)(m0 + wr * 32 + i * 16 + r0) * GATES +
                           (n0 + wc * 32 + j * 16 + cc);
#pragma unroll
      for (int r = 0; r < 4; ++r)
        Cp[rbase + (size_t)r * GATES] = acc[i][j][r];
    }
}

// ---------------- LSTM cell (float4): gates = XWb[f] + HW0 + HW1; update c,h ----------------
__global__ void lstm_cell2(const float* __restrict__ XW_f,  // (256x6144), biases included
                           const float* __restrict__ HW0,
                           const float* __restrict__ HW1,
                           float* __restrict__ c,
                           u16* __restrict__ h_bf,
                           float* __restrict__ hs_f,
                           int first) {
  int idx = blockIdx.x * blockDim.x + threadIdx.x;  // 98304: (b, q) with q in float4 units
  int b = idx / (HID / 4);
  int q = idx - b * (HID / 4);
  size_t rowq = (size_t)b * (GATES / 4);

  const float4* xw = (const float4*)XW_f;
  float4 gi = xw[rowq + q];
  float4 gf = xw[rowq + 384 + q];
  float4 gg = xw[rowq + 768 + q];
  float4 go = xw[rowq + 1152 + q];
  float4 cp = {0.f, 0.f, 0.f, 0.f};
  if (!first) {
    const float4* h0 = (const float4*)HW0;
    const float4* h1 = (const float4*)HW1;
    float4 u, v;
    u = h0[rowq + q];        v = h1[rowq + q];
    gi.x += u.x + v.x; gi.y += u.y + v.y; gi.z += u.z + v.z; gi.w += u.w + v.w;
    u = h0[rowq + 384 + q];  v = h1[rowq + 384 + q];
    gf.x += u.x + v.x; gf.y += u.y + v.y; gf.z += u.z + v.z; gf.w += u.w + v.w;
    u = h0[rowq + 768 + q];  v = h1[rowq + 768 + q];
    gg.x += u.x + v.x; gg.y += u.y + v.y; gg.z += u.z + v.z; gg.w += u.w + v.w;
    u = h0[rowq + 1152 + q]; v = h1[rowq + 1152 + q];
    go.x += u.x + v.x; go.y += u.y + v.y; go.z += u.z + v.z; go.w += u.w + v.w;
    cp = ((const float4*)c)[idx];
  }
  float4 cn, h;
  {
    float* pi = (float*)&gi; float* pf_ = (float*)&gf; float* pg = (float*)&gg;
    float* po = (float*)&go; float* pc = (float*)&cp;
    float* pcn = (float*)&cn; float* ph = (float*)&h;
#pragma unroll
    for (int e = 0; e < 4; ++e) {
      float cv = sigm(pf_[e]) * pc[e] + sigm(pi[e]) * tanhf(pg[e]);
      pcn[e] = cv;
      ph[e]  = tanhf(sigm(po[e]) * tanhf(cv));
    }
  }
  ((float4*)c)[idx] = cn;
  ((float4*)hs_f)[idx] = h;
  u16x4 hb = { f2bf(h.x), f2bf(h.y), f2bf(h.z), f2bf(h.w) };
  ((u16x4*)h_bf)[idx] = hb;
}

// ---------------- final: out[b,n,o] = relu(out2[b,n,:]) @ lin_W^T + lin_b ----------------
__global__ __launch_bounds__(256) void final_k(const float* __restrict__ hs,
                                               const float* __restrict__ lin_W,  // (12 x 36)
                                               const float* __restrict__ lin_b,  // (12)
                                               float* __restrict__ out) {
  __shared__ float Wsh[12 * 36];
  __shared__ float bsh[12];
  for (int i = threadIdx.x; i < 12 * 36; i += blockDim.x) Wsh[i] = lin_W[i];
  if (threadIdx.x < 12) bsh[threadIdx.x] = lin_b[threadIdx.x];
  __syncthreads();

  int idx = blockIdx.x * blockDim.x + threadIdx.x;  // (b*512 + n)
  int b = idx >> 9;
  int n = idx & 511;

  float acc[12];
#pragma unroll
  for (int o = 0; o < 12; ++o) acc[o] = bsh[o];

#pragma unroll
  for (int kk = 0; kk < 3; ++kk)
#pragma unroll
    for (int f = 0; f < 12; ++f) {
      float v = hs[(size_t)(f * BSZ + b) * HID + 3 * n + kk];
      v = fmaxf(v, 0.0f);
      int j = 12 * kk + f;
#pragma unroll
      for (int o = 0; o < 12; ++o) acc[o] += v * Wsh[o * 36 + j];
    }

#pragma unroll
  for (int o = 0; o < 12; ++o) out[(size_t)idx * 12 + o] = acc[o];
}

extern "C" void kernel_launch(void* const* d_in, const int* in_sizes, int n_in,
                              void* d_out, int out_size, void* d_ws, size_t ws_size,
                              hipStream_t stream) {
  (void)in_sizes; (void)n_in; (void)out_size; (void)ws_size;
  const float* X     = (const float*)d_in[1];
  const float* W_ih  = (const float*)d_in[2];
  const float* W_hh  = (const float*)d_in[3];
  const float* b_ih  = (const float*)d_in[4];
  const float* b_hh  = (const float*)d_in[5];
  const float* lin_W = (const float*)d_in[6];
  const float* lin_b = (const float*)d_in[7];
  float* out = (float*)d_out;

  // workspace layout (~235 MB total, unchanged footprint)
  char* p = (char*)d_ws;
  u16*   Ax   = (u16*)p;   p += (size_t)MROWS * INSZ * 2;
  u16*   Wihb = (u16*)p;   p += (size_t)GATES * INSZ * 2;
  u16*   Whhb = (u16*)p;   p += (size_t)GATES * HID * 2;
  float* XW   = (float*)p; p += (size_t)MROWS * GATES * 4;
  p += (size_t)BSZ * GATES * 4;   // (old HW slot, unused)
  u16*   hbf  = (u16*)p;   p += (size_t)BSZ * HID * 2;
  float* cbuf = (float*)p; p += (size_t)BSZ * HID * 4;
  float* hs   = (float*)p; p += (size_t)FF * BSZ * HID * 4;

  // HW0/HW1 alias the Ax region (Ax is dead after gemm8p; stream order serializes)
  float* HW0 = (float*)Ax;
  float* HW1 = HW0 + (size_t)BSZ * GATES;

  // raise dynamic-LDS cap for the 8-phase kernel (host-side, capture-safe)
  hipFuncSetAttribute((const void*)gemm8p,
                      hipFuncAttributeMaxDynamicSharedMemorySize, LDS_TOTAL);

  // 1) convert weights + pack X to bf16
  cvt_bf16<<<4096, 256, 0, stream>>>(W_ih, Wihb, (long)GATES * INSZ / 4);
  cvt_bf16<<<2048, 256, 0, stream>>>(W_hh, Whhb, (long)GATES * HID / 4);
  pack_x<<<(BSZ * INSZ) / 256, 256, 0, stream>>>(X, Ax);

  // 2) hoisted input GEMM (+ fused biases): XW = Ax @ W_ih^T + b_ih + b_hh
  gemm8p<<<256, 512, LDS_TOTAL, stream>>>(Ax, Wihb, b_ih, b_hh, XW,
                                          MROWS, GATES, INSZ);

  // 3) 12 sequential LSTM steps (splitK=2 GEMM + fused-sum cell)
  for (int f = 0; f < FF; ++f) {
    if (f > 0)
      gemm_step<<<dim3(GATES / 64, BSZ / 64, 2), 256, 0, stream>>>(hbf, Whhb, HW0);
    lstm_cell2<<<(BSZ * HID / 4) / 256, 256, 0, stream>>>(
        XW + (size_t)f * BSZ * GATES, HW0, HW1, cbuf, hbf,
        hs + (size_t)f * BSZ * HID, f == 0 ? 1 : 0);
  }

  // 4) final linear
  final_k<<<(BSZ * NN) / 256, 256, 0, stream>>>(hs, lin_W, lin_b, out);
}

// Round 7
// 540.545 us; speedup vs baseline: 1.4308x; 1.4308x over previous
//
#include <hip/hip_runtime.h>
#include <hip/hip_bf16.h>
#include <stdint.h>

typedef uint16_t u16;
typedef __attribute__((ext_vector_type(8))) __bf16 bf16x8;
typedef __attribute__((ext_vector_type(4))) float f32x4;
typedef __attribute__((ext_vector_type(4))) u16 u16x4;

// Problem constants
#define BSZ   256
#define NN    512
#define TT    12
#define FF    12
#define HID   1536
#define INSZ  6144    // N*F = LSTM input size
#define GATES 6144    // 4*HID
#define MROWS 3072    // FF*BSZ rows of the hoisted input GEMM
#define SPLITK 4
#define KSPL  (HID / SPLITK)   // 384

static __device__ __forceinline__ u16 f2bf(float x) {
  uint32_t u = __builtin_bit_cast(uint32_t, x);
  u += 0x7fffu + ((u >> 16) & 1u);   // RNE
  return (u16)(u >> 16);
}

static __device__ __forceinline__ float sigm(float x) {
  return 1.0f / (1.0f + expf(-x));
}

// ---------------- fp32 -> bf16 convert (4 elems/thread, grid-stride) ----------------
__global__ void cvt_bf16(const float* __restrict__ in, u16* __restrict__ out, long n4) {
  long stride = (long)gridDim.x * blockDim.x;
  for (long i = (long)blockIdx.x * blockDim.x + threadIdx.x; i < n4; i += stride) {
    float4 v = ((const float4*)in)[i];
    u16x4 r = { f2bf(v.x), f2bf(v.y), f2bf(v.z), f2bf(v.w) };
    ((u16x4*)out)[i] = r;
  }
}

// ---------------- pack X (B,N,T,F) -> A (MROWS=f*256+b, 6144=k) bf16 ----------------
__global__ void pack_x(const float* __restrict__ X, u16* __restrict__ Ax) {
  int idx = blockIdx.x * blockDim.x + threadIdx.x;   // one (b,k) per thread
  int b = idx / INSZ;
  int k = idx - b * INSZ;
  const float* xp = X + (size_t)b * (INSZ * FF) + (size_t)k * FF;
  float v[FF];
#pragma unroll
  for (int f = 0; f < FF; ++f) v[f] = xp[f];
#pragma unroll
  for (int f = 0; f < FF; ++f)
    Ax[(size_t)(f * BSZ + b) * INSZ + k] = f2bf(v[f]);
}

// =====================================================================
// Deep-pipelined bf16 GEMM (R5 version, known-good 229 us): 4 phases,
// 7 barriers/K-tile, short fragment live ranges (fits 128 VGPR, no spill).
// Tile 192x384, BK=64, 512 threads (8 waves, 2x4), per-wave 96x96.
// =====================================================================
#define BM8 192
#define BN8 384
#define LDSA_SZ 24576   // 192*64*2
#define LDSB_SZ 49152   // 384*64*2
#define LDS_TOTAL (2 * (LDSA_SZ + LDSB_SZ))   // 147456

#define GLL(src, dst)                                                          \
  __builtin_amdgcn_global_load_lds(                                            \
      (const __attribute__((address_space(1))) void*)(src),                    \
      (__attribute__((address_space(3))) void*)(dst), 16, 0, 0)

#define SBAR() asm volatile("s_barrier" ::: "memory")
#define WAIT_LGKM0()                                                           \
  do {                                                                         \
    asm volatile("s_waitcnt lgkmcnt(0)" ::: "memory");                         \
    __builtin_amdgcn_sched_barrier(0);                                         \
  } while (0)

__global__ __launch_bounds__(512, 2) void gemm8p(
    const u16* __restrict__ A, const u16* __restrict__ Bt,
    const float* __restrict__ bi, const float* __restrict__ bh,
    float* __restrict__ C, int M, int N, int K) {
  extern __shared__ __align__(16) char lds[];
  const int tid  = threadIdx.x;
  const int lane = tid & 63;
  const int wid  = tid >> 6;
  const int wr   = wid >> 2;   // 0..1
  const int wc   = wid & 3;    // 0..3

  // bijective XCD swizzle (gridDim.x % 8 == 0)
  const int nbx  = N / BN8;
  const int cpx  = gridDim.x >> 3;
  const int orig = blockIdx.x;
  const int wgid = (orig & 7) * cpx + (orig >> 3);
  const int m0   = (wgid / nbx) * BM8;
  const int n0   = (wgid % nbx) * BN8;

  // fragment-read per-lane constants (logical colbyte ^ ((row&7)<<4))
  const int fr    = lane & 15;
  const int kb    = (lane >> 4) << 4;
  const int swz   = (fr & 7) << 4;
  const int colp0 = kb ^ swz;          // kstep 0
  const int colp1 = (64 | kb) ^ swz;   // kstep 1

  // staging per-lane constants: linear LDS dest, inverse-swizzled source
  const int srow = tid >> 3;                                  // 0..63
  const int scb  = ((tid & 7) << 4) ^ ((srow & 7) << 4);      // byte col
  const u16* gA = A  + (size_t)(m0 + srow) * K + (scb >> 1);
  const u16* gB = Bt + (size_t)(n0 + srow) * K + (scb >> 1);
  const int wdst = wid << 10;   // wid*1024 bytes (lane*16 added by HW)

  char* ldsA = lds;
  char* ldsB = lds + 2 * LDSA_SZ;
  char* aRowB = ldsA + (wr * 96 + fr) * 128;   // + p*LDSA_SZ at use
  char* bRowB = ldsB + (wc * 96 + fr) * 128;   // + p*LDSB_SZ at use

  f32x4 acc[6][6] = {};
  const int NT = K >> 6;

  // prologue: stage tile 0 into buffer 0 (3 A chunks + 6 B chunks)
#pragma unroll
  for (int c = 0; c < 3; ++c) GLL(gA + (size_t)c * 64 * K, ldsA + c * 8192 + wdst);
#pragma unroll
  for (int c = 0; c < 6; ++c) GLL(gB + (size_t)c * 64 * K, ldsB + c * 8192 + wdst);

  for (int t = 0; t < NT; ++t) {
    const int p = t & 1;
    char* aRow = aRowB + p * LDSA_SZ;
    char* bRow = bRowB + p * LDSB_SZ;
    char* An = ldsA + (p ^ 1) * LDSA_SZ;
    char* Bn = ldsB + (p ^ 1) * LDSB_SZ;
    const u16* gAn = gA + (size_t)(t + 1) * 64;
    const u16* gBn = gB + (size_t)(t + 1) * 64;
    const bool pf = (t + 1 < NT);

    bf16x8 a[2][3], bb0[2][3], bb1[2][3];

    // ---------- phase 0: stage A(t+1); wait tile t; read a-qm0 + b-qn0; MFMA qm0 x qn0
    if (pf) {
#pragma unroll
      for (int c = 0; c < 3; ++c) GLL(gAn + (size_t)c * 64 * K, An + c * 8192 + wdst);
      asm volatile("s_waitcnt vmcnt(3)" ::: "memory");
    } else {
      asm volatile("s_waitcnt vmcnt(0)" ::: "memory");
    }
    SBAR();
#pragma unroll
    for (int i = 0; i < 3; ++i) {
      a[0][i]   = *(const bf16x8*)(aRow + i * 2048 + colp0);
      a[1][i]   = *(const bf16x8*)(aRow + i * 2048 + colp1);
      bb0[0][i] = *(const bf16x8*)(bRow + i * 2048 + colp0);
      bb0[1][i] = *(const bf16x8*)(bRow + i * 2048 + colp1);
    }
    WAIT_LGKM0();
    __builtin_amdgcn_s_setprio(1);
#pragma unroll
    for (int i = 0; i < 3; ++i)
#pragma unroll
      for (int j = 0; j < 3; ++j) {
        acc[i][j] = __builtin_amdgcn_mfma_f32_16x16x32_bf16(a[0][i], bb0[0][j], acc[i][j], 0, 0, 0);
        acc[i][j] = __builtin_amdgcn_mfma_f32_16x16x32_bf16(a[1][i], bb0[1][j], acc[i][j], 0, 0, 0);
      }
    __builtin_amdgcn_s_setprio(0);
    SBAR();

    // ---------- phase 1: read b-qn1; stage B(t+1) c0,c1; MFMA qm0 x qn1
#pragma unroll
    for (int i = 0; i < 3; ++i) {
      bb1[0][i] = *(const bf16x8*)(bRow + (3 + i) * 2048 + colp0);
      bb1[1][i] = *(const bf16x8*)(bRow + (3 + i) * 2048 + colp1);
    }
    if (pf) {
      GLL(gBn + (size_t)0 * 64 * K, Bn + 0 * 8192 + wdst);
      GLL(gBn + (size_t)1 * 64 * K, Bn + 1 * 8192 + wdst);
    }
    SBAR();
    WAIT_LGKM0();
    __builtin_amdgcn_s_setprio(1);
#pragma unroll
    for (int i = 0; i < 3; ++i)
#pragma unroll
      for (int j = 0; j < 3; ++j) {
        acc[i][3 + j] = __builtin_amdgcn_mfma_f32_16x16x32_bf16(a[0][i], bb1[0][j], acc[i][3 + j], 0, 0, 0);
        acc[i][3 + j] = __builtin_amdgcn_mfma_f32_16x16x32_bf16(a[1][i], bb1[1][j], acc[i][3 + j], 0, 0, 0);
      }
    __builtin_amdgcn_s_setprio(0);
    SBAR();

    // ---------- phase 2: read a-qm1; stage B(t+1) c2,c3; MFMA qm1 x qn1
#pragma unroll
    for (int i = 0; i < 3; ++i) {
      a[0][i] = *(const bf16x8*)(aRow + (3 + i) * 2048 + colp0);
      a[1][i] = *(const bf16x8*)(aRow + (3 + i) * 2048 + colp1);
    }
    if (pf) {
      GLL(gBn + (size_t)2 * 64 * K, Bn + 2 * 8192 + wdst);
      GLL(gBn + (size_t)3 * 64 * K, Bn + 3 * 8192 + wdst);
    }
    SBAR();
    WAIT_LGKM0();
    __builtin_amdgcn_s_setprio(1);
#pragma unroll
    for (int i = 0; i < 3; ++i)
#pragma unroll
      for (int j = 0; j < 3; ++j) {
        acc[3 + i][3 + j] = __builtin_amdgcn_mfma_f32_16x16x32_bf16(a[0][i], bb1[0][j], acc[3 + i][3 + j], 0, 0, 0);
        acc[3 + i][3 + j] = __builtin_amdgcn_mfma_f32_16x16x32_bf16(a[1][i], bb1[1][j], acc[3 + i][3 + j], 0, 0, 0);
      }
    __builtin_amdgcn_s_setprio(0);
    SBAR();

    // ---------- phase 3: stage B(t+1) c4,c5; MFMA qm1 x qn0 (bb0 still in regs)
    if (pf) {
      GLL(gBn + (size_t)4 * 64 * K, Bn + 4 * 8192 + wdst);
      GLL(gBn + (size_t)5 * 64 * K, Bn + 5 * 8192 + wdst);
    }
    __builtin_amdgcn_s_setprio(1);
#pragma unroll
    for (int i = 0; i < 3; ++i)
#pragma unroll
      for (int j = 0; j < 3; ++j) {
        acc[3 + i][j] = __builtin_amdgcn_mfma_f32_16x16x32_bf16(a[0][i], bb0[0][j], acc[3 + i][j], 0, 0, 0);
        acc[3 + i][j] = __builtin_amdgcn_mfma_f32_16x16x32_bf16(a[1][i], bb0[1][j], acc[3 + i][j], 0, 0, 0);
      }
    __builtin_amdgcn_s_setprio(0);
    SBAR();
  }

  // epilogue: C = acc + (b_ih + b_hh)[col]
  const int r0 = (lane >> 4) << 2;
  const int cc = lane & 15;
#pragma unroll
  for (int j = 0; j < 6; ++j) {
    const int col = n0 + wc * 96 + j * 16 + cc;
    const float bv = bi[col] + bh[col];
#pragma unroll
    for (int i = 0; i < 6; ++i) {
      const size_t rbase = (size_t)(m0 + wr * 96 + i * 16 + r0) * N + col;
#pragma unroll
      for (int r = 0; r < 4; ++r)
        C[rbase + (size_t)r * N] = acc[i][j][r] + bv;
    }
  }
}

// =====================================================================
// SplitK=4 pipelined step GEMM: HW_s(256x6144) = h(256x384-qtr) @ Whh^T
// 64x64 tile, BK=64, 4 waves (each a 32x32 quadrant), dbuf LDS 32KB,
// counted vmcnt(4), grid (96,4,4) = 1536 blocks = 6/CU (4 resident).
// Shorter serial K-chain (6 iters) + 2x TLP vs splitK=2.
// =====================================================================
__global__ __launch_bounds__(256, 4) void gemm_step(
    const u16* __restrict__ A,   // hbf (256 x 1536)
    const u16* __restrict__ Bt,  // Whhb (6144 x 1536)
    float* __restrict__ HW) {    // partials: split s at HW + s*BSZ*GATES
  __shared__ __align__(16) char lds[32768];
  const int tid  = threadIdx.x;
  const int lane = tid & 63;
  const int wid  = tid >> 6;
  const int wr   = wid >> 1;   // 0..1
  const int wc   = wid & 1;    // 0..1
  const int n0   = blockIdx.x * 64;
  const int m0   = blockIdx.y * 64;
  const int s    = blockIdx.z;
  const int K    = HID;
  const int koff = s * KSPL;

  // fragment-read constants (same scheme as gemm8p)
  const int fr    = lane & 15;
  const int kb    = (lane >> 4) << 4;
  const int swz   = (fr & 7) << 4;
  const int colp0 = kb ^ swz;
  const int colp1 = (64 | kb) ^ swz;

  // staging: thread t -> row = t>>3 (0..31), cb = (t&7)*16; chunk 1 adds 32 rows
  const int srow = tid >> 3;
  const int scb  = ((tid & 7) << 4) ^ ((srow & 7) << 4);
  const u16* gA = A  + (size_t)(m0 + srow) * K + koff + (scb >> 1);
  const u16* gB = Bt + (size_t)(n0 + srow) * K + koff + (scb >> 1);
  const int wdst = wid << 10;

  char* ldsA = lds;            // [2][8192]
  char* ldsB = lds + 16384;    // [2][8192]
  char* aRowB = ldsA + (wr * 32 + fr) * 128;
  char* bRowB = ldsB + (wc * 32 + fr) * 128;

  f32x4 acc[2][2] = {};
  const int NT = KSPL >> 6;   // 6

  // prologue: stage tile 0 into buffer 0
  GLL(gA,                    ldsA + wdst);
  GLL(gA + (size_t)32 * K,   ldsA + 4096 + wdst);
  GLL(gB,                    ldsB + wdst);
  GLL(gB + (size_t)32 * K,   ldsB + 4096 + wdst);

  for (int t = 0; t < NT; ++t) {
    const int p = t & 1;
    char* aRow = aRowB + p * 8192;
    char* bRow = bRowB + p * 8192;
    char* An = ldsA + (p ^ 1) * 8192;
    char* Bn = ldsB + (p ^ 1) * 8192;
    const u16* gAn = gA + (size_t)(t + 1) * 64;
    const u16* gBn = gB + (size_t)(t + 1) * 64;

    if (t + 1 < NT) {
      GLL(gAn,                  An + wdst);
      GLL(gAn + (size_t)32 * K, An + 4096 + wdst);
      GLL(gBn,                  Bn + wdst);
      GLL(gBn + (size_t)32 * K, Bn + 4096 + wdst);
      asm volatile("s_waitcnt vmcnt(4)" ::: "memory");
    } else {
      asm volatile("s_waitcnt vmcnt(0)" ::: "memory");
    }
    SBAR();

    bf16x8 a[2][2], b[2][2];
#pragma unroll
    for (int i = 0; i < 2; ++i) {
      a[0][i] = *(const bf16x8*)(aRow + i * 2048 + colp0);
      a[1][i] = *(const bf16x8*)(aRow + i * 2048 + colp1);
      b[0][i] = *(const bf16x8*)(bRow + i * 2048 + colp0);
      b[1][i] = *(const bf16x8*)(bRow + i * 2048 + colp1);
    }
    WAIT_LGKM0();
    __builtin_amdgcn_s_setprio(1);
#pragma unroll
    for (int i = 0; i < 2; ++i)
#pragma unroll
      for (int j = 0; j < 2; ++j) {
        acc[i][j] = __builtin_amdgcn_mfma_f32_16x16x32_bf16(a[0][i], b[0][j], acc[i][j], 0, 0, 0);
        acc[i][j] = __builtin_amdgcn_mfma_f32_16x16x32_bf16(a[1][i], b[1][j], acc[i][j], 0, 0, 0);
      }
    __builtin_amdgcn_s_setprio(0);
    SBAR();
  }

  float* Cp = HW + (size_t)s * BSZ * GATES;
  const int r0 = (lane >> 4) << 2;
  const int cc = lane & 15;
#pragma unroll
  for (int i = 0; i < 2; ++i)
#pragma unroll
    for (int j = 0; j < 2; ++j) {
      const size_t rbase = (size_t)(m0 + wr * 32 + i * 16 + r0) * GATES +
                           (n0 + wc * 32 + j * 16 + cc);
#pragma unroll
      for (int r = 0; r < 4; ++r)
        Cp[rbase + (size_t)r * GATES] = acc[i][j][r];
    }
}

// ---------------- LSTM cell (float4): gates = XWb[f] + sum_s HW_s; update c,h ----------------
__global__ void lstm_cell2(const float* __restrict__ XW_f,  // (256x6144), biases included
                           const float* __restrict__ HWb,   // 4 partials, stride BSZ*GATES
                           float* __restrict__ c,
                           u16* __restrict__ h_bf,
                           float* __restrict__ hs_f,
                           int first) {
  int idx = blockIdx.x * blockDim.x + threadIdx.x;  // 98304: (b, q) with q in float4 units
  int b = idx / (HID / 4);
  int q = idx - b * (HID / 4);
  size_t rowq = (size_t)b * (GATES / 4);

  const float4* xw = (const float4*)XW_f;
  float4 gi = xw[rowq + q];
  float4 gf = xw[rowq + 384 + q];
  float4 gg = xw[rowq + 768 + q];
  float4 go = xw[rowq + 1152 + q];
  float4 cp = {0.f, 0.f, 0.f, 0.f};
  if (!first) {
#pragma unroll
    for (int s = 0; s < SPLITK; ++s) {
      const float4* hg = (const float4*)(HWb + (size_t)s * BSZ * GATES);
      float4 u;
      u = hg[rowq + q];
      gi.x += u.x; gi.y += u.y; gi.z += u.z; gi.w += u.w;
      u = hg[rowq + 384 + q];
      gf.x += u.x; gf.y += u.y; gf.z += u.z; gf.w += u.w;
      u = hg[rowq + 768 + q];
      gg.x += u.x; gg.y += u.y; gg.z += u.z; gg.w += u.w;
      u = hg[rowq + 1152 + q];
      go.x += u.x; go.y += u.y; go.z += u.z; go.w += u.w;
    }
    cp = ((const float4*)c)[idx];
  }
  float4 cn, h;
  {
    float* pi = (float*)&gi; float* pf_ = (float*)&gf; float* pg = (float*)&gg;
    float* po = (float*)&go; float* pc = (float*)&cp;
    float* pcn = (float*)&cn; float* ph = (float*)&h;
#pragma unroll
    for (int e = 0; e < 4; ++e) {
      float cv = sigm(pf_[e]) * pc[e] + sigm(pi[e]) * tanhf(pg[e]);
      pcn[e] = cv;
      ph[e]  = tanhf(sigm(po[e]) * tanhf(cv));
    }
  }
  ((float4*)c)[idx] = cn;
  ((float4*)hs_f)[idx] = h;
  u16x4 hb = { f2bf(h.x), f2bf(h.y), f2bf(h.z), f2bf(h.w) };
  ((u16x4*)h_bf)[idx] = hb;
}

// ---------------- final: out[b,n,o] = relu(out2[b,n,:]) @ lin_W^T + lin_b ----------------
__global__ __launch_bounds__(256) void final_k(const float* __restrict__ hs,
                                               const float* __restrict__ lin_W,  // (12 x 36)
                                               const float* __restrict__ lin_b,  // (12)
                                               float* __restrict__ out) {
  __shared__ float Wsh[12 * 36];
  __shared__ float bsh[12];
  for (int i = threadIdx.x; i < 12 * 36; i += blockDim.x) Wsh[i] = lin_W[i];
  if (threadIdx.x < 12) bsh[threadIdx.x] = lin_b[threadIdx.x];
  __syncthreads();

  int idx = blockIdx.x * blockDim.x + threadIdx.x;  // (b*512 + n)
  int b = idx >> 9;
  int n = idx & 511;

  float acc[12];
#pragma unroll
  for (int o = 0; o < 12; ++o) acc[o] = bsh[o];

#pragma unroll
  for (int kk = 0; kk < 3; ++kk)
#pragma unroll
    for (int f = 0; f < 12; ++f) {
      float v = hs[(size_t)(f * BSZ + b) * HID + 3 * n + kk];
      v = fmaxf(v, 0.0f);
      int j = 12 * kk + f;
#pragma unroll
      for (int o = 0; o < 12; ++o) acc[o] += v * Wsh[o * 36 + j];
    }

#pragma unroll
  for (int o = 0; o < 12; ++o) out[(size_t)idx * 12 + o] = acc[o];
}

extern "C" void kernel_launch(void* const* d_in, const int* in_sizes, int n_in,
                              void* d_out, int out_size, void* d_ws, size_t ws_size,
                              hipStream_t stream) {
  (void)in_sizes; (void)n_in; (void)out_size; (void)ws_size;
  const float* X     = (const float*)d_in[1];
  const float* W_ih  = (const float*)d_in[2];
  const float* W_hh  = (const float*)d_in[3];
  const float* b_ih  = (const float*)d_in[4];
  const float* b_hh  = (const float*)d_in[5];
  const float* lin_W = (const float*)d_in[6];
  const float* lin_b = (const float*)d_in[7];
  float* out = (float*)d_out;

  // workspace layout (~235 MB total, unchanged footprint)
  char* p = (char*)d_ws;
  u16*   Ax   = (u16*)p;   p += (size_t)MROWS * INSZ * 2;
  u16*   Wihb = (u16*)p;   p += (size_t)GATES * INSZ * 2;
  u16*   Whhb = (u16*)p;   p += (size_t)GATES * HID * 2;
  float* XW   = (float*)p; p += (size_t)MROWS * GATES * 4;
  p += (size_t)BSZ * GATES * 4;   // (old HW slot, unused)
  u16*   hbf  = (u16*)p;   p += (size_t)BSZ * HID * 2;
  float* cbuf = (float*)p; p += (size_t)BSZ * HID * 4;
  float* hs   = (float*)p; p += (size_t)FF * BSZ * HID * 4;

  // HW partials (4 x 6.3 MB = 25.2 MB) alias the Ax region (dead after gemm8p)
  float* HW0 = (float*)Ax;

  // raise dynamic-LDS cap for the big GEMM (host-side, capture-safe)
  hipFuncSetAttribute((const void*)gemm8p,
                      hipFuncAttributeMaxDynamicSharedMemorySize, LDS_TOTAL);

  // 1) convert weights + pack X to bf16
  cvt_bf16<<<4096, 256, 0, stream>>>(W_ih, Wihb, (long)GATES * INSZ / 4);
  cvt_bf16<<<2048, 256, 0, stream>>>(W_hh, Whhb, (long)GATES * HID / 4);
  pack_x<<<(BSZ * INSZ) / 256, 256, 0, stream>>>(X, Ax);

  // 2) hoisted input GEMM (+ fused biases): XW = Ax @ W_ih^T + b_ih + b_hh
  gemm8p<<<256, 512, LDS_TOTAL, stream>>>(Ax, Wihb, b_ih, b_hh, XW,
                                          MROWS, GATES, INSZ);

  // 3) 12 sequential LSTM steps (splitK=4 GEMM + fused-sum cell)
  for (int f = 0; f < FF; ++f) {
    if (f > 0)
      gemm_step<<<dim3(GATES / 64, BSZ / 64, SPLITK), 256, 0, stream>>>(hbf, Whhb, HW0);
    lstm_cell2<<<(BSZ * HID / 4) / 256, 256, 0, stream>>>(
        XW + (size_t)f * BSZ * GATES, HW0, cbuf, hbf,
        hs + (size_t)f * BSZ * HID, f == 0 ? 1 : 0);
  }

  // 4) final linear
  final_k<<<(BSZ * NN) / 256, 256, 0, stream>>>(hs, lin_W, lin_b, out);
}

// Round 8
// 494.438 us; speedup vs baseline: 1.5642x; 1.0932x over previous
//
#include <hip/hip_runtime.h>
#include <hip/hip_bf16.h>
#include <stdint.h>

typedef uint16_t u16;
typedef __attribute__((ext_vector_type(8))) __bf16 bf16x8;
typedef __attribute__((ext_vector_type(4))) float f32x4;
typedef __attribute__((ext_vector_type(4))) u16 u16x4;

// Problem constants
#define BSZ   256
#define NN    512
#define TT    12
#define FF    12
#define HID   1536
#define INSZ  6144    // N*F = LSTM input size
#define GATES 6144    // 4*HID
#define MROWS 3072    // FF*BSZ rows of the hoisted input GEMM
#define SPLITK 2
#define KSPL  (HID / SPLITK)   // 768

static __device__ __forceinline__ u16 f2bf(float x) {
  uint32_t u = __builtin_bit_cast(uint32_t, x);
  u += 0x7fffu + ((u >> 16) & 1u);   // RNE
  return (u16)(u >> 16);
}

static __device__ __forceinline__ float sigm(float x) {
  return 1.0f / (1.0f + expf(-x));
}

// ---------------- fp32 -> bf16 convert (4 elems/thread, grid-stride) ----------------
__global__ void cvt_bf16(const float* __restrict__ in, u16* __restrict__ out, long n4) {
  long stride = (long)gridDim.x * blockDim.x;
  for (long i = (long)blockIdx.x * blockDim.x + threadIdx.x; i < n4; i += stride) {
    float4 v = ((const float4*)in)[i];
    u16x4 r = { f2bf(v.x), f2bf(v.y), f2bf(v.z), f2bf(v.w) };
    ((u16x4*)out)[i] = r;
  }
}

// ---------------- pack X (B,N,T,F) -> A (MROWS=f*256+b, 6144=k) bf16 ----------------
__global__ void pack_x(const float* __restrict__ X, u16* __restrict__ Ax) {
  int idx = blockIdx.x * blockDim.x + threadIdx.x;   // one (b,k) per thread
  int b = idx / INSZ;
  int k = idx - b * INSZ;
  const float* xp = X + (size_t)b * (INSZ * FF) + (size_t)k * FF;
  float v[FF];
#pragma unroll
  for (int f = 0; f < FF; ++f) v[f] = xp[f];
#pragma unroll
  for (int f = 0; f < FF; ++f)
    Ax[(size_t)(f * BSZ + b) * INSZ + k] = f2bf(v[f]);
}

// =====================================================================
// Deep-pipelined bf16 GEMM: C(MxN) = A(MxK) * Bt(NxK)^T + bias
// Tile 192x384, BK=64, 512 threads (8 waves, 2x4), per-wave 96x96.
// R8: 2 barriers/K-tile + wave drift. Register discipline vs R6's spill:
//  - launch_bounds(512,1): LDS already forces 1 block/CU; VGPR cap -> 256
//  - 3 read groups, reuse order (max 3 fragment sets = 72 VGPR live)
//  - sched_barrier(0x7F) between clusters: DS reads can't hoist across
//    (everything else schedules freely). Tripwire: WRITE_SIZE ~74MB.
// =====================================================================
#define BM8 192
#define BN8 384
#define LDSA_SZ 24576   // 192*64*2
#define LDSB_SZ 49152   // 384*64*2
#define LDS_TOTAL (2 * (LDSA_SZ + LDSB_SZ))   // 147456

#define GLL(src, dst)                                                          \
  __builtin_amdgcn_global_load_lds(                                            \
      (const __attribute__((address_space(1))) void*)(src),                    \
      (__attribute__((address_space(3))) void*)(dst), 16, 0, 0)

#define SBAR() asm volatile("s_barrier" ::: "memory")
#define SCHED_FENCE_DS() __builtin_amdgcn_sched_barrier(0x7F)  // block DS ops only

__global__ __launch_bounds__(512, 1) void gemm8p(
    const u16* __restrict__ A, const u16* __restrict__ Bt,
    const float* __restrict__ bi, const float* __restrict__ bh,
    float* __restrict__ C, int M, int N, int K) {
  extern __shared__ __align__(16) char lds[];
  const int tid  = threadIdx.x;
  const int lane = tid & 63;
  const int wid  = tid >> 6;
  const int wr   = wid >> 2;   // 0..1
  const int wc   = wid & 3;    // 0..3

  // bijective XCD swizzle (gridDim.x % 8 == 0)
  const int nbx  = N / BN8;
  const int cpx  = gridDim.x >> 3;
  const int orig = blockIdx.x;
  const int wgid = (orig & 7) * cpx + (orig >> 3);
  const int m0   = (wgid / nbx) * BM8;
  const int n0   = (wgid % nbx) * BN8;

  // fragment-read per-lane constants (logical colbyte ^ ((row&7)<<4))
  const int fr    = lane & 15;
  const int kb    = (lane >> 4) << 4;
  const int swz   = (fr & 7) << 4;
  const int colp0 = kb ^ swz;          // kstep 0
  const int colp1 = (64 | kb) ^ swz;   // kstep 1

  // staging per-lane constants: linear LDS dest, inverse-swizzled source
  const int srow = tid >> 3;                                  // 0..63
  const int scb  = ((tid & 7) << 4) ^ ((srow & 7) << 4);      // byte col
  const u16* gA = A  + (size_t)(m0 + srow) * K + (scb >> 1);
  const u16* gB = Bt + (size_t)(n0 + srow) * K + (scb >> 1);
  const int wdst = wid << 10;   // wid*1024 bytes (lane*16 added by HW)

  char* ldsA = lds;
  char* ldsB = lds + 2 * LDSA_SZ;
  char* aRowB = ldsA + (wr * 96 + fr) * 128;   // + p*LDSA_SZ at use
  char* bRowB = ldsB + (wc * 96 + fr) * 128;   // + p*LDSB_SZ at use

  f32x4 acc[6][6] = {};
  const int NT = K >> 6;

  // prologue: stage tile 0 into buffer 0 (3 A chunks + 6 B chunks)
#pragma unroll
  for (int c = 0; c < 3; ++c) GLL(gA + (size_t)c * 64 * K, ldsA + c * 8192 + wdst);
#pragma unroll
  for (int c = 0; c < 6; ++c) GLL(gB + (size_t)c * 64 * K, ldsB + c * 8192 + wdst);

  for (int t = 0; t < NT; ++t) {
    const int p = t & 1;
    char* aRow = aRowB + p * LDSA_SZ;
    char* bRow = bRowB + p * LDSB_SZ;
    char* An = ldsA + (p ^ 1) * LDSA_SZ;
    char* Bn = ldsB + (p ^ 1) * LDSB_SZ;
    const u16* gAn = gA + (size_t)(t + 1) * 64;
    const u16* gBn = gB + (size_t)(t + 1) * 64;
    const bool pf = (t + 1 < NT);

    bf16x8 a0[2][3], a1[2][3], b0[2][3], b1[2][3];

    // ---- iter entry: stage A(t+1); wait tile t staged; visibility barrier
    if (pf) {
#pragma unroll
      for (int c = 0; c < 3; ++c) GLL(gAn + (size_t)c * 64 * K, An + c * 8192 + wdst);
      asm volatile("s_waitcnt vmcnt(3)" ::: "memory");
    } else {
      asm volatile("s_waitcnt vmcnt(0)" ::: "memory");
    }
    SBAR();

    // ---- group 0: read a0,b0 (2 sets live); q00
#pragma unroll
    for (int i = 0; i < 3; ++i) {
      a0[0][i] = *(const bf16x8*)(aRow + i * 2048 + colp0);
      a0[1][i] = *(const bf16x8*)(aRow + i * 2048 + colp1);
      b0[0][i] = *(const bf16x8*)(bRow + i * 2048 + colp0);
      b0[1][i] = *(const bf16x8*)(bRow + i * 2048 + colp1);
    }
    __builtin_amdgcn_s_setprio(1);
#pragma unroll
    for (int i = 0; i < 3; ++i)
#pragma unroll
      for (int j = 0; j < 3; ++j) {
        acc[i][j] = __builtin_amdgcn_mfma_f32_16x16x32_bf16(a0[0][i], b0[0][j], acc[i][j], 0, 0, 0);
        acc[i][j] = __builtin_amdgcn_mfma_f32_16x16x32_bf16(a0[1][i], b0[1][j], acc[i][j], 0, 0, 0);
      }
    __builtin_amdgcn_s_setprio(0);
    if (pf) {
      GLL(gBn + (size_t)0 * 64 * K, Bn + 0 * 8192 + wdst);
      GLL(gBn + (size_t)1 * 64 * K, Bn + 1 * 8192 + wdst);
    }
    SCHED_FENCE_DS();

    // ---- group 1: read b1 (a0,b0,b1 live = 3 sets); q01 = a0 x b1; a0 dies
#pragma unroll
    for (int i = 0; i < 3; ++i) {
      b1[0][i] = *(const bf16x8*)(bRow + (3 + i) * 2048 + colp0);
      b1[1][i] = *(const bf16x8*)(bRow + (3 + i) * 2048 + colp1);
    }
    __builtin_amdgcn_s_setprio(1);
#pragma unroll
    for (int i = 0; i < 3; ++i)
#pragma unroll
      for (int j = 0; j < 3; ++j) {
        acc[i][3 + j] = __builtin_amdgcn_mfma_f32_16x16x32_bf16(a0[0][i], b1[0][j], acc[i][3 + j], 0, 0, 0);
        acc[i][3 + j] = __builtin_amdgcn_mfma_f32_16x16x32_bf16(a0[1][i], b1[1][j], acc[i][3 + j], 0, 0, 0);
      }
    __builtin_amdgcn_s_setprio(0);
    if (pf) {
      GLL(gBn + (size_t)2 * 64 * K, Bn + 2 * 8192 + wdst);
      GLL(gBn + (size_t)3 * 64 * K, Bn + 3 * 8192 + wdst);
    }
    SCHED_FENCE_DS();

    // ---- group 2: read a1 (b0,b1,a1 live = 3 sets); q11 = a1 x b1; b1 dies
#pragma unroll
    for (int i = 0; i < 3; ++i) {
      a1[0][i] = *(const bf16x8*)(aRow + (3 + i) * 2048 + colp0);
      a1[1][i] = *(const bf16x8*)(aRow + (3 + i) * 2048 + colp1);
    }
    __builtin_amdgcn_s_setprio(1);
#pragma unroll
    for (int i = 0; i < 3; ++i)
#pragma unroll
      for (int j = 0; j < 3; ++j) {
        acc[3 + i][3 + j] = __builtin_amdgcn_mfma_f32_16x16x32_bf16(a1[0][i], b1[0][j], acc[3 + i][3 + j], 0, 0, 0);
        acc[3 + i][3 + j] = __builtin_amdgcn_mfma_f32_16x16x32_bf16(a1[1][i], b1[1][j], acc[3 + i][3 + j], 0, 0, 0);
      }
    __builtin_amdgcn_s_setprio(0);
    if (pf) {
      GLL(gBn + (size_t)4 * 64 * K, Bn + 4 * 8192 + wdst);
      GLL(gBn + (size_t)5 * 64 * K, Bn + 5 * 8192 + wdst);
    }
    SCHED_FENCE_DS();

    // ---- group 3: q10 = a1 x b0 (both still live, no reads)
    __builtin_amdgcn_s_setprio(1);
#pragma unroll
    for (int i = 0; i < 3; ++i)
#pragma unroll
      for (int j = 0; j < 3; ++j) {
        acc[3 + i][j] = __builtin_amdgcn_mfma_f32_16x16x32_bf16(a1[0][i], b0[0][j], acc[3 + i][j], 0, 0, 0);
        acc[3 + i][j] = __builtin_amdgcn_mfma_f32_16x16x32_bf16(a1[1][i], b0[1][j], acc[3 + i][j], 0, 0, 0);
      }
    __builtin_amdgcn_s_setprio(0);

    // ---- end-of-iter: every ds_read above was consumed by an MFMA (compiler
    // emits the lgkmcnt waits), so reads of buffer p are drained. Barrier
    // before any wave's next-iter GLLs overwrite buffer p.
    SBAR();
  }

  // epilogue: C = acc + (b_ih + b_hh)[col]
  const int r0 = (lane >> 4) << 2;
  const int cc = lane & 15;
#pragma unroll
  for (int j = 0; j < 6; ++j) {
    const int col = n0 + wc * 96 + j * 16 + cc;
    const float bv = bi[col] + bh[col];
#pragma unroll
    for (int i = 0; i < 6; ++i) {
      const size_t rbase = (size_t)(m0 + wr * 96 + i * 16 + r0) * N + col;
#pragma unroll
      for (int r = 0; r < 4; ++r)
        C[rbase + (size_t)r * N] = acc[i][j][r] + bv;
    }
  }
}

// =====================================================================
// SplitK=2 pipelined step GEMM (R5 config, known-good): 64x64 tile, BK=64,
// 4 waves, dbuf LDS 32KB, counted vmcnt(4), grid (96,4,2) = 768 blocks.
// =====================================================================
#define WAIT_LGKM0()                                                           \
  do {                                                                         \
    asm volatile("s_waitcnt lgkmcnt(0)" ::: "memory");                         \
    __builtin_amdgcn_sched_barrier(0);                                         \
  } while (0)

__global__ __launch_bounds__(256, 4) void gemm_step(
    const u16* __restrict__ A,   // hbf (256 x 1536)
    const u16* __restrict__ Bt,  // Whhb (6144 x 1536)
    float* __restrict__ HW) {    // partials: split s at HW + s*BSZ*GATES
  __shared__ __align__(16) char lds[32768];
  const int tid  = threadIdx.x;
  const int lane = tid & 63;
  const int wid  = tid >> 6;
  const int wr   = wid >> 1;   // 0..1
  const int wc   = wid & 1;    // 0..1
  const int n0   = blockIdx.x * 64;
  const int m0   = blockIdx.y * 64;
  const int s    = blockIdx.z;
  const int K    = HID;
  const int koff = s * KSPL;

  // fragment-read constants (same scheme as gemm8p)
  const int fr    = lane & 15;
  const int kb    = (lane >> 4) << 4;
  const int swz   = (fr & 7) << 4;
  const int colp0 = kb ^ swz;
  const int colp1 = (64 | kb) ^ swz;

  // staging: thread t -> row = t>>3 (0..31), cb = (t&7)*16; chunk 1 adds 32 rows
  const int srow = tid >> 3;
  const int scb  = ((tid & 7) << 4) ^ ((srow & 7) << 4);
  const u16* gA = A  + (size_t)(m0 + srow) * K + koff + (scb >> 1);
  const u16* gB = Bt + (size_t)(n0 + srow) * K + koff + (scb >> 1);
  const int wdst = wid << 10;

  char* ldsA = lds;            // [2][8192]
  char* ldsB = lds + 16384;    // [2][8192]
  char* aRowB = ldsA + (wr * 32 + fr) * 128;
  char* bRowB = ldsB + (wc * 32 + fr) * 128;

  f32x4 acc[2][2] = {};
  const int NT = KSPL >> 6;   // 12

  // prologue: stage tile 0 into buffer 0
  GLL(gA,                    ldsA + wdst);
  GLL(gA + (size_t)32 * K,   ldsA + 4096 + wdst);
  GLL(gB,                    ldsB + wdst);
  GLL(gB + (size_t)32 * K,   ldsB + 4096 + wdst);

  for (int t = 0; t < NT; ++t) {
    const int p = t & 1;
    char* aRow = aRowB + p * 8192;
    char* bRow = bRowB + p * 8192;
    char* An = ldsA + (p ^ 1) * 8192;
    char* Bn = ldsB + (p ^ 1) * 8192;
    const u16* gAn = gA + (size_t)(t + 1) * 64;
    const u16* gBn = gB + (size_t)(t + 1) * 64;

    if (t + 1 < NT) {
      GLL(gAn,                  An + wdst);
      GLL(gAn + (size_t)32 * K, An + 4096 + wdst);
      GLL(gBn,                  Bn + wdst);
      GLL(gBn + (size_t)32 * K, Bn + 4096 + wdst);
      asm volatile("s_waitcnt vmcnt(4)" ::: "memory");
    } else {
      asm volatile("s_waitcnt vmcnt(0)" ::: "memory");
    }
    SBAR();

    bf16x8 a[2][2], b[2][2];
#pragma unroll
    for (int i = 0; i < 2; ++i) {
      a[0][i] = *(const bf16x8*)(aRow + i * 2048 + colp0);
      a[1][i] = *(const bf16x8*)(aRow + i * 2048 + colp1);
      b[0][i] = *(const bf16x8*)(bRow + i * 2048 + colp0);
      b[1][i] = *(const bf16x8*)(bRow + i * 2048 + colp1);
    }
    WAIT_LGKM0();
    __builtin_amdgcn_s_setprio(1);
#pragma unroll
    for (int i = 0; i < 2; ++i)
#pragma unroll
      for (int j = 0; j < 2; ++j) {
        acc[i][j] = __builtin_amdgcn_mfma_f32_16x16x32_bf16(a[0][i], b[0][j], acc[i][j], 0, 0, 0);
        acc[i][j] = __builtin_amdgcn_mfma_f32_16x16x32_bf16(a[1][i], b[1][j], acc[i][j], 0, 0, 0);
      }
    __builtin_amdgcn_s_setprio(0);
    SBAR();
  }

  float* Cp = HW + (size_t)s * BSZ * GATES;
  const int r0 = (lane >> 4) << 2;
  const int cc = lane & 15;
#pragma unroll
  for (int i = 0; i < 2; ++i)
#pragma unroll
    for (int j = 0; j < 2; ++j) {
      const size_t rbase = (size_t)(m0 + wr * 32 + i * 16 + r0) * GATES +
                           (n0 + wc * 32 + j * 16 + cc);
#pragma unroll
      for (int r = 0; r < 4; ++r)
        Cp[rbase + (size_t)r * GATES] = acc[i][j][r];
    }
}

// ---------------- LSTM cell (float4): gates = XWb[f] + sum_s HW_s; update c,h ----------------
__global__ void lstm_cell2(const float* __restrict__ XW_f,  // (256x6144), biases included
                           const float* __restrict__ HWb,   // SPLITK partials, stride BSZ*GATES
                           float* __restrict__ c,
                           u16* __restrict__ h_bf,
                           float* __restrict__ hs_f,
                           int first) {
  int idx = blockIdx.x * blockDim.x + threadIdx.x;  // 98304: (b, q) with q in float4 units
  int b = idx / (HID / 4);
  int q = idx - b * (HID / 4);
  size_t rowq = (size_t)b * (GATES / 4);

  const float4* xw = (const float4*)XW_f;
  float4 gi = xw[rowq + q];
  float4 gf = xw[rowq + 384 + q];
  float4 gg = xw[rowq + 768 + q];
  float4 go = xw[rowq + 1152 + q];
  float4 cp = {0.f, 0.f, 0.f, 0.f};
  if (!first) {
#pragma unroll
    for (int s = 0; s < SPLITK; ++s) {
      const float4* hg = (const float4*)(HWb + (size_t)s * BSZ * GATES);
      float4 u;
      u = hg[rowq + q];
      gi.x += u.x; gi.y += u.y; gi.z += u.z; gi.w += u.w;
      u = hg[rowq + 384 + q];
      gf.x += u.x; gf.y += u.y; gf.z += u.z; gf.w += u.w;
      u = hg[rowq + 768 + q];
      gg.x += u.x; gg.y += u.y; gg.z += u.z; gg.w += u.w;
      u = hg[rowq + 1152 + q];
      go.x += u.x; go.y += u.y; go.z += u.z; go.w += u.w;
    }
    cp = ((const float4*)c)[idx];
  }
  float4 cn, h;
  {
    float* pi = (float*)&gi; float* pf_ = (float*)&gf; float* pg = (float*)&gg;
    float* po = (float*)&go; float* pc = (float*)&cp;
    float* pcn = (float*)&cn; float* ph = (float*)&h;
#pragma unroll
    for (int e = 0; e < 4; ++e) {
      float cv = sigm(pf_[e]) * pc[e] + sigm(pi[e]) * tanhf(pg[e]);
      pcn[e] = cv;
      ph[e]  = tanhf(sigm(po[e]) * tanhf(cv));
    }
  }
  ((float4*)c)[idx] = cn;
  ((float4*)hs_f)[idx] = h;
  u16x4 hb = { f2bf(h.x), f2bf(h.y), f2bf(h.z), f2bf(h.w) };
  ((u16x4*)h_bf)[idx] = hb;
}

// ---------------- final: out[b,n,o] = relu(out2[b,n,:]) @ lin_W^T + lin_b ----------------
__global__ __launch_bounds__(256) void final_k(const float* __restrict__ hs,
                                               const float* __restrict__ lin_W,  // (12 x 36)
                                               const float* __restrict__ lin_b,  // (12)
                                               float* __restrict__ out) {
  __shared__ float Wsh[12 * 36];
  __shared__ float bsh[12];
  for (int i = threadIdx.x; i < 12 * 36; i += blockDim.x) Wsh[i] = lin_W[i];
  if (threadIdx.x < 12) bsh[threadIdx.x] = lin_b[threadIdx.x];
  __syncthreads();

  int idx = blockIdx.x * blockDim.x + threadIdx.x;  // (b*512 + n)
  int b = idx >> 9;
  int n = idx & 511;

  float acc[12];
#pragma unroll
  for (int o = 0; o < 12; ++o) acc[o] = bsh[o];

#pragma unroll
  for (int kk = 0; kk < 3; ++kk)
#pragma unroll
    for (int f = 0; f < 12; ++f) {
      float v = hs[(size_t)(f * BSZ + b) * HID + 3 * n + kk];
      v = fmaxf(v, 0.0f);
      int j = 12 * kk + f;
#pragma unroll
      for (int o = 0; o < 12; ++o) acc[o] += v * Wsh[o * 36 + j];
    }

#pragma unroll
  for (int o = 0; o < 12; ++o) out[(size_t)idx * 12 + o] = acc[o];
}

extern "C" void kernel_launch(void* const* d_in, const int* in_sizes, int n_in,
                              void* d_out, int out_size, void* d_ws, size_t ws_size,
                              hipStream_t stream) {
  (void)in_sizes; (void)n_in; (void)out_size; (void)ws_size;
  const float* X     = (const float*)d_in[1];
  const float* W_ih  = (const float*)d_in[2];
  const float* W_hh  = (const float*)d_in[3];
  const float* b_ih  = (const float*)d_in[4];
  const float* b_hh  = (const float*)d_in[5];
  const float* lin_W = (const float*)d_in[6];
  const float* lin_b = (const float*)d_in[7];
  float* out = (float*)d_out;

  // workspace layout (~235 MB total, unchanged footprint)
  char* p = (char*)d_ws;
  u16*   Ax   = (u16*)p;   p += (size_t)MROWS * INSZ * 2;
  u16*   Wihb = (u16*)p;   p += (size_t)GATES * INSZ * 2;
  u16*   Whhb = (u16*)p;   p += (size_t)GATES * HID * 2;
  float* XW   = (float*)p; p += (size_t)MROWS * GATES * 4;
  p += (size_t)BSZ * GATES * 4;   // (old HW slot, unused)
  u16*   hbf  = (u16*)p;   p += (size_t)BSZ * HID * 2;
  float* cbuf = (float*)p; p += (size_t)BSZ * HID * 4;
  float* hs   = (float*)p; p += (size_t)FF * BSZ * HID * 4;

  // HW partials (2 x 6.3 MB) alias the Ax region (dead after gemm8p)
  float* HW0 = (float*)Ax;

  // raise dynamic-LDS cap for the big GEMM (host-side, capture-safe)
  hipFuncSetAttribute((const void*)gemm8p,
                      hipFuncAttributeMaxDynamicSharedMemorySize, LDS_TOTAL);

  // 1) convert weights + pack X to bf16
  cvt_bf16<<<4096, 256, 0, stream>>>(W_ih, Wihb, (long)GATES * INSZ / 4);
  cvt_bf16<<<2048, 256, 0, stream>>>(W_hh, Whhb, (long)GATES * HID / 4);
  pack_x<<<(BSZ * INSZ) / 256, 256, 0, stream>>>(X, Ax);

  // 2) hoisted input GEMM (+ fused biases): XW = Ax @ W_ih^T + b_ih + b_hh
  gemm8p<<<256, 512, LDS_TOTAL, stream>>>(Ax, Wihb, b_ih, b_hh, XW,
                                          MROWS, GATES, INSZ);

  // 3) 12 sequential LSTM steps (splitK=2 GEMM + fused-sum cell)
  for (int f = 0; f < FF; ++f) {
    if (f > 0)
      gemm_step<<<dim3(GATES / 64, BSZ / 64, SPLITK), 256, 0, stream>>>(hbf, Whhb, HW0);
    lstm_cell2<<<(BSZ * HID / 4) / 256, 256, 0, stream>>>(
        XW + (size_t)f * BSZ * GATES, HW0, cbuf, hbf,
        hs + (size_t)f * BSZ * HID, f == 0 ? 1 : 0);
  }

  // 4) final linear
  final_k<<<(BSZ * NN) / 256, 256, 0, stream>>>(hs, lin_W, lin_b, out);
}